// Round 2
// baseline (16712.326 us; speedup 1.0000x reference)
//
#include <hip/hip_runtime.h>
#include <hip/hip_bf16.h>

typedef _Float16 half8 __attribute__((ext_vector_type(8)));
typedef float floatx4 __attribute__((ext_vector_type(4)));

__device__ __constant__ float NF4_TAB[16] = {
    -1.0f, -0.6961928009986877f, -0.5250730514526367f, -0.39491748809814453f,
    -0.28444138169288635f, -0.18477343022823334f, -0.09105003625154495f, 0.0f,
    0.07958029955625534f, 0.16093020141124725f, 0.24611230194568634f,
    0.33791524171829224f, 0.44070982933044434f, 0.5626170039176941f,
    0.7229568362236023f, 1.0f};

typedef __attribute__((address_space(3))) void lds_t;
typedef __attribute__((address_space(1))) void gbl_t;

__device__ __forceinline__ void gload16(const void* g, void* l) {
  __builtin_amdgcn_global_load_lds((gbl_t*)g, (lds_t*)l, 16, 0, 0);
}

// ---------------- x f32 -> f16 ----------------
__global__ void cvt_f32_to_f16(const float* __restrict__ in,
                               _Float16* __restrict__ out, int total8) {
  int stride = gridDim.x * blockDim.x;
  for (int i = blockIdx.x * blockDim.x + threadIdx.x; i < total8; i += stride) {
    long e = (long)i * 8;
    const float4* ip = reinterpret_cast<const float4*>(in + e);
    float4 a = ip[0], b = ip[1];
    half8 o;
    o[0] = (_Float16)a.x; o[1] = (_Float16)a.y;
    o[2] = (_Float16)a.z; o[3] = (_Float16)a.w;
    o[4] = (_Float16)b.x; o[5] = (_Float16)b.y;
    o[6] = (_Float16)b.z; o[7] = (_Float16)b.w;
    *reinterpret_cast<half8*>(out + e) = o;
  }
}

// ---------------- NF4 dequant: codes[R,C] + scales[R,C/64] -> f16 [R,C] ----
__global__ void dequant_nf4(const int* __restrict__ codes,
                            const float* __restrict__ scales,
                            _Float16* __restrict__ out,
                            int total8, int C, int CB) {
  __shared__ float lut[16];
  if (threadIdx.x < 16) lut[threadIdx.x] = NF4_TAB[threadIdx.x];
  __syncthreads();
  int stride = gridDim.x * blockDim.x;
  for (int i = blockIdx.x * blockDim.x + threadIdx.x; i < total8; i += stride) {
    long e = (long)i * 8;
    int row = (int)(e / C);
    int col = (int)(e - (long)row * C);
    float sc = scales[row * CB + (col >> 6)];
    const int4* cp = reinterpret_cast<const int4*>(codes + e);
    int4 c0 = cp[0];
    int4 c1 = cp[1];
    half8 o;
    o[0] = (_Float16)(lut[c0.x & 15] * sc);
    o[1] = (_Float16)(lut[c0.y & 15] * sc);
    o[2] = (_Float16)(lut[c0.z & 15] * sc);
    o[3] = (_Float16)(lut[c0.w & 15] * sc);
    o[4] = (_Float16)(lut[c1.x & 15] * sc);
    o[5] = (_Float16)(lut[c1.y & 15] * sc);
    o[6] = (_Float16)(lut[c1.z & 15] * sc);
    o[7] = (_Float16)(lut[c1.w & 15] * sc);
    *reinterpret_cast<half8*>(out + e) = o;
  }
}

// ---------------- GEMM1: h = silu(x Wg^T) * (x Wu^T), f16 out ----------------
// X [8192,4096], Wg/Wu [11008,4096] row-major (K contiguous both) -> H [8192,11008]
// LDS chunk-XOR swizzle: physical chunk = logical chunk ^ (row&3).
// Staged via linear global_load_lds with pre-permuted GLOBAL source (rule #21).
__global__ __launch_bounds__(256, 4) void gemm_gateup(
    const _Float16* __restrict__ X,
    const _Float16* __restrict__ Wg,
    const _Float16* __restrict__ Wu,
    _Float16* __restrict__ H) {
  constexpr int K = 4096;
  constexpr long M = 11008;
  __shared__ __align__(16) _Float16 sA[128][32];
  __shared__ __align__(16) _Float16 sG[128][32];
  __shared__ __align__(16) _Float16 sU[128][32];

  const int t = threadIdx.x;
  const int lane = t & 63, wave = t >> 6;
  const int wr = wave >> 1, wc = wave & 1;

  // supertile remap: 2 N-bands of 43 tiles; within band sweep all 64 T-tiles
  const int bid = blockIdx.y * 86 + blockIdx.x;
  const int band = bid / (43 * 64);
  const int r = bid % (43 * 64);
  const int bc = band * 43 + (r % 43);
  const int br = r / 43;

  const int srow = t >> 2;                       // 0..63 (tile row; +64 for 2nd gload)
  const int lc = (t & 3) ^ (srow & 3);           // logical chunk this thread fetches
  // (srow+64)&3 == srow&3, so lc is valid for both gloads

  const _Float16* pA = X + (long)(br * 128 + srow) * K + lc * 8;
  const _Float16* pG = Wg + (long)(bc * 128 + srow) * K + lc * 8;
  const _Float16* pU = Wu + (long)(bc * 128 + srow) * K + lc * 8;

  _Float16* dA = &sA[srow][(t & 3) * 8];  // linear t*16B within wave
  _Float16* dG = &sG[srow][(t & 3) * 8];
  _Float16* dU = &sU[srow][(t & 3) * 8];

  floatx4 accG[4][4] = {};
  floatx4 accU[4][4] = {};

  const int rA = wr * 64 + (lane & 15);
  const int rB = wc * 64 + (lane & 15);
  const int pkA = (((lane >> 4) ^ (rA & 3)) * 8);  // physical chunk offset (elems)
  const int pkB = (((lane >> 4) ^ (rB & 3)) * 8);  // (rA+16i)&3 == rA&3

  for (int kk = 0; kk < K; kk += 32) {
    gload16(pA, dA);
    gload16(pA + (long)64 * K, dA + 64 * 32);
    gload16(pG, dG);
    gload16(pG + (long)64 * K, dG + 64 * 32);
    gload16(pU, dU);
    gload16(pU + (long)64 * K, dU + 64 * 32);
    pA += 32; pG += 32; pU += 32;
    __syncthreads();

    half8 a[4], bg[4], bu[4];
#pragma unroll
    for (int i = 0; i < 4; ++i) {
      a[i]  = *reinterpret_cast<const half8*>(&sA[rA + 16 * i][pkA]);
      bg[i] = *reinterpret_cast<const half8*>(&sG[rB + 16 * i][pkB]);
      bu[i] = *reinterpret_cast<const half8*>(&sU[rB + 16 * i][pkB]);
    }
#pragma unroll
    for (int i = 0; i < 4; ++i) {
#pragma unroll
      for (int j = 0; j < 4; ++j) {
        accG[i][j] = __builtin_amdgcn_mfma_f32_16x16x32_f16(a[i], bg[j], accG[i][j], 0, 0, 0);
        accU[i][j] = __builtin_amdgcn_mfma_f32_16x16x32_f16(a[i], bu[j], accU[i][j], 0, 0, 0);
      }
    }
    __syncthreads();
  }

  // epilogue: h = silu(g)*u, C/D layout col=lane&15, row=(lane>>4)*4+ii
  const int tr0 = br * 128 + wr * 64 + (lane >> 4) * 4;
  const int mc0 = bc * 128 + wc * 64 + (lane & 15);
#pragma unroll
  for (int i = 0; i < 4; ++i) {
#pragma unroll
    for (int j = 0; j < 4; ++j) {
#pragma unroll
      for (int ii = 0; ii < 4; ++ii) {
        float g = accG[i][j][ii];
        float u = accU[i][j][ii];
        float s = g / (1.0f + __expf(-g));
        H[(long)(tr0 + i * 16 + ii) * M + (mc0 + j * 16)] = (_Float16)(s * u);
      }
    }
  }
}

// ---------------- GEMM2: out = h Wd^T, f32 out ----------------
// H [8192,11008], Wd [4096,11008] row-major -> O [8192,4096] f32
__global__ __launch_bounds__(256, 4) void gemm_down(
    const _Float16* __restrict__ Hm,
    const _Float16* __restrict__ Wd,
    float* __restrict__ O) {
  constexpr int K = 11008;
  constexpr long N = 4096;
  __shared__ __align__(16) _Float16 sA[128][32];
  __shared__ __align__(16) _Float16 sB[128][32];

  const int t = threadIdx.x;
  const int lane = t & 63, wave = t >> 6;
  const int wr = wave >> 1, wc = wave & 1;
  const int br = blockIdx.y, bc = blockIdx.x;  // x=N (32 tiles): Wd stays LLC-resident

  const int srow = t >> 2;
  const int lc = (t & 3) ^ (srow & 3);

  const _Float16* pA = Hm + (long)(br * 128 + srow) * K + lc * 8;
  const _Float16* pB = Wd + (long)(bc * 128 + srow) * K + lc * 8;

  _Float16* dA = &sA[srow][(t & 3) * 8];
  _Float16* dB = &sB[srow][(t & 3) * 8];

  floatx4 acc[4][4] = {};

  const int rA = wr * 64 + (lane & 15);
  const int rB = wc * 64 + (lane & 15);
  const int pkA = (((lane >> 4) ^ (rA & 3)) * 8);
  const int pkB = (((lane >> 4) ^ (rB & 3)) * 8);

  for (int kk = 0; kk < K; kk += 32) {
    gload16(pA, dA);
    gload16(pA + (long)64 * K, dA + 64 * 32);
    gload16(pB, dB);
    gload16(pB + (long)64 * K, dB + 64 * 32);
    pA += 32; pB += 32;
    __syncthreads();

    half8 a[4], b[4];
#pragma unroll
    for (int i = 0; i < 4; ++i) {
      a[i] = *reinterpret_cast<const half8*>(&sA[rA + 16 * i][pkA]);
      b[i] = *reinterpret_cast<const half8*>(&sB[rB + 16 * i][pkB]);
    }
#pragma unroll
    for (int i = 0; i < 4; ++i) {
#pragma unroll
      for (int j = 0; j < 4; ++j) {
        acc[i][j] = __builtin_amdgcn_mfma_f32_16x16x32_f16(a[i], b[j], acc[i][j], 0, 0, 0);
      }
    }
    __syncthreads();
  }

  const int tr0 = br * 128 + wr * 64 + (lane >> 4) * 4;
  const int dc0 = bc * 128 + wc * 64 + (lane & 15);
#pragma unroll
  for (int i = 0; i < 4; ++i) {
#pragma unroll
    for (int j = 0; j < 4; ++j) {
#pragma unroll
      for (int ii = 0; ii < 4; ++ii) {
        O[(long)(tr0 + i * 16 + ii) * N + (dc0 + j * 16)] = acc[i][j][ii];
      }
    }
  }
}

extern "C" void kernel_launch(void* const* d_in, const int* in_sizes, int n_in,
                              void* d_out, int out_size, void* d_ws, size_t ws_size,
                              hipStream_t stream) {
  const float* x           = (const float*)d_in[0];
  const int*   gate_codes  = (const int*)d_in[1];
  const float* gate_scales = (const float*)d_in[2];
  const int*   up_codes    = (const int*)d_in[3];
  const float* up_scales   = (const float*)d_in[4];
  const int*   down_codes  = (const int*)d_in[5];
  const float* down_scales = (const float*)d_in[6];
  float* out = (float*)d_out;

  const long T = 8192, HD = 4096, M = 11008;

  // ws layout (fp16): x16 [T,HD] | Wa [M,HD] | Wb [M,HD] | h16 [T,M]
  char* ws = (char*)d_ws;
  _Float16* x16 = (_Float16*)ws;
  _Float16* Wa  = (_Float16*)(ws + T * HD * 2);
  _Float16* Wb  = (_Float16*)(ws + T * HD * 2 + M * HD * 2);
  _Float16* h16 = (_Float16*)(ws + T * HD * 2 + 2 * M * HD * 2);

  cvt_f32_to_f16<<<2048, 256, 0, stream>>>(x, x16, (int)(T * HD / 8));
  dequant_nf4<<<2048, 256, 0, stream>>>(gate_codes, gate_scales, Wa,
                                        (int)(M * HD / 8), (int)HD, (int)(HD / 64));
  dequant_nf4<<<2048, 256, 0, stream>>>(up_codes, up_scales, Wb,
                                        (int)(M * HD / 8), (int)HD, (int)(HD / 64));

  dim3 g1((unsigned)(M / 128), (unsigned)(T / 128));
  gemm_gateup<<<g1, 256, 0, stream>>>(x16, Wa, Wb, h16);

  // reuse Wa for down weights
  dequant_nf4<<<2048, 256, 0, stream>>>(down_codes, down_scales, Wa,
                                        (int)(HD * M / 8), (int)M, (int)(M / 64));

  dim3 g2((unsigned)(HD / 128), (unsigned)(T / 128));
  gemm_down<<<g2, 256, 0, stream>>>(h16, Wa, out);
}

// Round 3
// 3291.589 us; speedup vs baseline: 5.0773x; 5.0773x over previous
//
#include <hip/hip_runtime.h>
#include <hip/hip_bf16.h>

typedef _Float16 half8 __attribute__((ext_vector_type(8)));
typedef float floatx4 __attribute__((ext_vector_type(4)));

__device__ __constant__ float NF4_TAB[16] = {
    -1.0f, -0.6961928009986877f, -0.5250730514526367f, -0.39491748809814453f,
    -0.28444138169288635f, -0.18477343022823334f, -0.09105003625154495f, 0.0f,
    0.07958029955625534f, 0.16093020141124725f, 0.24611230194568634f,
    0.33791524171829224f, 0.44070982933044434f, 0.5626170039176941f,
    0.7229568362236023f, 1.0f};

typedef __attribute__((address_space(3))) void lds_t;
typedef __attribute__((address_space(1))) void gbl_t;

__device__ __forceinline__ void gload16(const void* g, void* l) {
  __builtin_amdgcn_global_load_lds((gbl_t*)g, (lds_t*)l, 16, 0, 0);
}

// ---------------- x f32 -> f16 ----------------
__global__ void cvt_f32_to_f16(const float* __restrict__ in,
                               _Float16* __restrict__ out, int total8) {
  int stride = gridDim.x * blockDim.x;
  for (int i = blockIdx.x * blockDim.x + threadIdx.x; i < total8; i += stride) {
    long e = (long)i * 8;
    const float4* ip = reinterpret_cast<const float4*>(in + e);
    float4 a = ip[0], b = ip[1];
    half8 o;
    o[0] = (_Float16)a.x; o[1] = (_Float16)a.y;
    o[2] = (_Float16)a.z; o[3] = (_Float16)a.w;
    o[4] = (_Float16)b.x; o[5] = (_Float16)b.y;
    o[6] = (_Float16)b.z; o[7] = (_Float16)b.w;
    *reinterpret_cast<half8*>(out + e) = o;
  }
}

// ---------------- NF4 dequant: codes[R,C] + scales[R,C/64] -> f16 [R,C] ----
__global__ void dequant_nf4(const int* __restrict__ codes,
                            const float* __restrict__ scales,
                            _Float16* __restrict__ out,
                            int total8, int C, int CB) {
  __shared__ float lut[16];
  if (threadIdx.x < 16) lut[threadIdx.x] = NF4_TAB[threadIdx.x];
  __syncthreads();
  int stride = gridDim.x * blockDim.x;
  for (int i = blockIdx.x * blockDim.x + threadIdx.x; i < total8; i += stride) {
    long e = (long)i * 8;
    int row = (int)(e / C);
    int col = (int)(e - (long)row * C);
    float sc = scales[row * CB + (col >> 6)];
    const int4* cp = reinterpret_cast<const int4*>(codes + e);
    int4 c0 = cp[0];
    int4 c1 = cp[1];
    half8 o;
    o[0] = (_Float16)(lut[c0.x & 15] * sc);
    o[1] = (_Float16)(lut[c0.y & 15] * sc);
    o[2] = (_Float16)(lut[c0.z & 15] * sc);
    o[3] = (_Float16)(lut[c0.w & 15] * sc);
    o[4] = (_Float16)(lut[c1.x & 15] * sc);
    o[5] = (_Float16)(lut[c1.y & 15] * sc);
    o[6] = (_Float16)(lut[c1.z & 15] * sc);
    o[7] = (_Float16)(lut[c1.w & 15] * sc);
    *reinterpret_cast<half8*>(out + e) = o;
  }
}

// LDS chunk swizzle: physical chunk p at row r holds global chunk p ^ h(r),
// h(r) = (r>>1)&3. Read-group bank-slot (4r + chunk) mod 8 -> each of 8
// b128 slots hit exactly 2x per 16 lanes = conflict-free (2-way is free).
// Staged via linear global_load_lds dest + pre-permuted GLOBAL source.

// ---------------- GEMM1: h = silu(x Wg^T) * (x Wu^T), f16 out ----------------
// X [8192,4096], Wg/Wu [11008,4096] row-major -> H [8192,11008]
__global__ __launch_bounds__(256, 2) void gemm_gateup(
    const _Float16* __restrict__ X,
    const _Float16* __restrict__ Wg,
    const _Float16* __restrict__ Wu,
    _Float16* __restrict__ H) {
  constexpr int K = 4096;
  constexpr long M = 11008;
  __shared__ __align__(16) _Float16 sA[128][32];
  __shared__ __align__(16) _Float16 sG[128][32];
  __shared__ __align__(16) _Float16 sU[128][32];

  const int t = threadIdx.x;
  const int lane = t & 63, wave = t >> 6;
  const int wr = wave >> 1, wc = wave & 1;

  // supertile remap: 2 N-bands of 43 tiles; within band sweep all 64 T-tiles.
  // working set/band ~110 MB < 256 MB LLC -> weights fetched ~once.
  const int bid = blockIdx.y * 86 + blockIdx.x;
  const int band = bid / (43 * 64);
  const int r = bid % (43 * 64);
  const int bc = band * 43 + (r % 43);
  const int br = r / 43;

  const int srow = t >> 2;                      // 0..63 (+64 for 2nd gload)
  const int lc = (t & 3) ^ ((t >> 3) & 3);      // global chunk; h(srow)=h(srow+64)

  const _Float16* pA = X + (long)(br * 128 + srow) * K + lc * 8;
  const _Float16* pG = Wg + (long)(bc * 128 + srow) * K + lc * 8;
  const _Float16* pU = Wu + (long)(bc * 128 + srow) * K + lc * 8;

  _Float16* dA = &sA[srow][(t & 3) * 8];  // linear t*16B within wave
  _Float16* dG = &sG[srow][(t & 3) * 8];
  _Float16* dU = &sU[srow][(t & 3) * 8];

  floatx4 accG[4][4] = {};
  floatx4 accU[4][4] = {};

  const int rA = wr * 64 + (lane & 15);
  const int rB = wc * 64 + (lane & 15);
  const int pkA = (((lane >> 4) ^ ((rA >> 1) & 3)) * 8);  // phys chunk (elems)
  const int pkB = (((lane >> 4) ^ ((rB >> 1) & 3)) * 8);  // h(r+16i)==h(r)

  for (int kk = 0; kk < K; kk += 32) {
    gload16(pA, dA);
    gload16(pA + (long)64 * K, dA + 64 * 32);
    gload16(pG, dG);
    gload16(pG + (long)64 * K, dG + 64 * 32);
    gload16(pU, dU);
    gload16(pU + (long)64 * K, dU + 64 * 32);
    pA += 32; pG += 32; pU += 32;
    __syncthreads();

    half8 a[4], bg[4], bu[4];
#pragma unroll
    for (int i = 0; i < 4; ++i) {
      a[i]  = *reinterpret_cast<const half8*>(&sA[rA + 16 * i][pkA]);
      bg[i] = *reinterpret_cast<const half8*>(&sG[rB + 16 * i][pkB]);
      bu[i] = *reinterpret_cast<const half8*>(&sU[rB + 16 * i][pkB]);
    }
#pragma unroll
    for (int i = 0; i < 4; ++i) {
#pragma unroll
      for (int j = 0; j < 4; ++j) {
        accG[i][j] = __builtin_amdgcn_mfma_f32_16x16x32_f16(a[i], bg[j], accG[i][j], 0, 0, 0);
        accU[i][j] = __builtin_amdgcn_mfma_f32_16x16x32_f16(a[i], bu[j], accU[i][j], 0, 0, 0);
      }
    }
    __syncthreads();
  }

  // epilogue: h = silu(g)*u, C/D layout col=lane&15, row=(lane>>4)*4+ii
  const int tr0 = br * 128 + wr * 64 + (lane >> 4) * 4;
  const int mc0 = bc * 128 + wc * 64 + (lane & 15);
#pragma unroll
  for (int i = 0; i < 4; ++i) {
#pragma unroll
    for (int j = 0; j < 4; ++j) {
#pragma unroll
      for (int ii = 0; ii < 4; ++ii) {
        float g = accG[i][j][ii];
        float u = accU[i][j][ii];
        float s = g / (1.0f + __expf(-g));
        H[(long)(tr0 + i * 16 + ii) * M + (mc0 + j * 16)] = (_Float16)(s * u);
      }
    }
  }
}

// ---------------- GEMM2: out = h Wd^T, f32 out ----------------
// H [8192,11008], Wd [4096,11008] row-major -> O [8192,4096] f32
__global__ __launch_bounds__(256, 2) void gemm_down(
    const _Float16* __restrict__ Hm,
    const _Float16* __restrict__ Wd,
    float* __restrict__ O) {
  constexpr int K = 11008;
  constexpr long N = 4096;
  __shared__ __align__(16) _Float16 sA[128][32];
  __shared__ __align__(16) _Float16 sB[128][32];

  const int t = threadIdx.x;
  const int lane = t & 63, wave = t >> 6;
  const int wr = wave >> 1, wc = wave & 1;
  const int br = blockIdx.y, bc = blockIdx.x;  // x=N (32 tiles): Wd LLC-resident

  const int srow = t >> 2;
  const int lc = (t & 3) ^ ((t >> 3) & 3);

  const _Float16* pA = Hm + (long)(br * 128 + srow) * K + lc * 8;
  const _Float16* pB = Wd + (long)(bc * 128 + srow) * K + lc * 8;

  _Float16* dA = &sA[srow][(t & 3) * 8];
  _Float16* dB = &sB[srow][(t & 3) * 8];

  floatx4 acc[4][4] = {};

  const int rA = wr * 64 + (lane & 15);
  const int rB = wc * 64 + (lane & 15);
  const int pkA = (((lane >> 4) ^ ((rA >> 1) & 3)) * 8);
  const int pkB = (((lane >> 4) ^ ((rB >> 1) & 3)) * 8);

  for (int kk = 0; kk < K; kk += 32) {
    gload16(pA, dA);
    gload16(pA + (long)64 * K, dA + 64 * 32);
    gload16(pB, dB);
    gload16(pB + (long)64 * K, dB + 64 * 32);
    pA += 32; pB += 32;
    __syncthreads();

    half8 a[4], b[4];
#pragma unroll
    for (int i = 0; i < 4; ++i) {
      a[i] = *reinterpret_cast<const half8*>(&sA[rA + 16 * i][pkA]);
      b[i] = *reinterpret_cast<const half8*>(&sB[rB + 16 * i][pkB]);
    }
#pragma unroll
    for (int i = 0; i < 4; ++i) {
#pragma unroll
      for (int j = 0; j < 4; ++j) {
        acc[i][j] = __builtin_amdgcn_mfma_f32_16x16x32_f16(a[i], b[j], acc[i][j], 0, 0, 0);
      }
    }
    __syncthreads();
  }

  const int tr0 = br * 128 + wr * 64 + (lane >> 4) * 4;
  const int dc0 = bc * 128 + wc * 64 + (lane & 15);
#pragma unroll
  for (int i = 0; i < 4; ++i) {
#pragma unroll
    for (int j = 0; j < 4; ++j) {
#pragma unroll
      for (int ii = 0; ii < 4; ++ii) {
        O[(long)(tr0 + i * 16 + ii) * N + (dc0 + j * 16)] = acc[i][j][ii];
      }
    }
  }
}

extern "C" void kernel_launch(void* const* d_in, const int* in_sizes, int n_in,
                              void* d_out, int out_size, void* d_ws, size_t ws_size,
                              hipStream_t stream) {
  const float* x           = (const float*)d_in[0];
  const int*   gate_codes  = (const int*)d_in[1];
  const float* gate_scales = (const float*)d_in[2];
  const int*   up_codes    = (const int*)d_in[3];
  const float* up_scales   = (const float*)d_in[4];
  const int*   down_codes  = (const int*)d_in[5];
  const float* down_scales = (const float*)d_in[6];
  float* out = (float*)d_out;

  const long T = 8192, HD = 4096, M = 11008;

  // ws layout (fp16): x16 [T,HD] | Wa [M,HD] | Wb [M,HD] | h16 [T,M]
  char* ws = (char*)d_ws;
  _Float16* x16 = (_Float16*)ws;
  _Float16* Wa  = (_Float16*)(ws + T * HD * 2);
  _Float16* Wb  = (_Float16*)(ws + T * HD * 2 + M * HD * 2);
  _Float16* h16 = (_Float16*)(ws + T * HD * 2 + 2 * M * HD * 2);

  cvt_f32_to_f16<<<2048, 256, 0, stream>>>(x, x16, (int)(T * HD / 8));
  dequant_nf4<<<2048, 256, 0, stream>>>(gate_codes, gate_scales, Wa,
                                        (int)(M * HD / 8), (int)HD, (int)(HD / 64));
  dequant_nf4<<<2048, 256, 0, stream>>>(up_codes, up_scales, Wb,
                                        (int)(M * HD / 8), (int)HD, (int)(HD / 64));

  dim3 g1((unsigned)(M / 128), (unsigned)(T / 128));
  gemm_gateup<<<g1, 256, 0, stream>>>(x16, Wa, Wb, h16);

  // reuse Wa for down weights
  dequant_nf4<<<2048, 256, 0, stream>>>(down_codes, down_scales, Wa,
                                        (int)(HD * M / 8), (int)M, (int)(M / 64));

  dim3 g2((unsigned)(HD / 128), (unsigned)(T / 128));
  gemm_down<<<g2, 256, 0, stream>>>(h16, Wa, out);
}

// Round 4
// 2340.967 us; speedup vs baseline: 7.1391x; 1.4061x over previous
//
#include <hip/hip_runtime.h>
#include <hip/hip_bf16.h>

typedef _Float16 half8 __attribute__((ext_vector_type(8)));
typedef float floatx4 __attribute__((ext_vector_type(4)));

__device__ __constant__ float NF4_TAB[16] = {
    -1.0f, -0.6961928009986877f, -0.5250730514526367f, -0.39491748809814453f,
    -0.28444138169288635f, -0.18477343022823334f, -0.09105003625154495f, 0.0f,
    0.07958029955625534f, 0.16093020141124725f, 0.24611230194568634f,
    0.33791524171829224f, 0.44070982933044434f, 0.5626170039176941f,
    0.7229568362236023f, 1.0f};

typedef __attribute__((address_space(3))) void lds_t;
typedef __attribute__((address_space(1))) void gbl_t;

__device__ __forceinline__ void gload16(const void* g, void* l) {
  __builtin_amdgcn_global_load_lds((gbl_t*)g, (lds_t*)l, 16, 0, 0);
}

// ---------------- x f32 -> f16 ----------------
__global__ void cvt_f32_to_f16(const float* __restrict__ in,
                               _Float16* __restrict__ out, int total8) {
  int stride = gridDim.x * blockDim.x;
  for (int i = blockIdx.x * blockDim.x + threadIdx.x; i < total8; i += stride) {
    long e = (long)i * 8;
    const float4* ip = reinterpret_cast<const float4*>(in + e);
    float4 a = ip[0], b = ip[1];
    half8 o;
    o[0] = (_Float16)a.x; o[1] = (_Float16)a.y;
    o[2] = (_Float16)a.z; o[3] = (_Float16)a.w;
    o[4] = (_Float16)b.x; o[5] = (_Float16)b.y;
    o[6] = (_Float16)b.z; o[7] = (_Float16)b.w;
    *reinterpret_cast<half8*>(out + e) = o;
  }
}

// ---------------- NF4 dequant: codes[R,C] + scales[R,C/64] -> f16 [R,C] ----
__global__ void dequant_nf4(const int* __restrict__ codes,
                            const float* __restrict__ scales,
                            _Float16* __restrict__ out,
                            int total8, int C, int CB) {
  __shared__ float lut[16];
  if (threadIdx.x < 16) lut[threadIdx.x] = NF4_TAB[threadIdx.x];
  __syncthreads();
  int stride = gridDim.x * blockDim.x;
  for (int i = blockIdx.x * blockDim.x + threadIdx.x; i < total8; i += stride) {
    long e = (long)i * 8;
    int row = (int)(e / C);
    int col = (int)(e - (long)row * C);
    float sc = scales[row * CB + (col >> 6)];
    const int4* cp = reinterpret_cast<const int4*>(codes + e);
    int4 c0 = cp[0];
    int4 c1 = cp[1];
    half8 o;
    o[0] = (_Float16)(lut[c0.x & 15] * sc);
    o[1] = (_Float16)(lut[c0.y & 15] * sc);
    o[2] = (_Float16)(lut[c0.z & 15] * sc);
    o[3] = (_Float16)(lut[c0.w & 15] * sc);
    o[4] = (_Float16)(lut[c1.x & 15] * sc);
    o[5] = (_Float16)(lut[c1.y & 15] * sc);
    o[6] = (_Float16)(lut[c1.z & 15] * sc);
    o[7] = (_Float16)(lut[c1.w & 15] * sc);
    *reinterpret_cast<half8*>(out + e) = o;
  }
}

// =====================================================================
// 256x256 GEMM, BK=32, 8 waves (2Mx4N), per-wave 128x64 output.
// 3-buffer LDS rotation (32 KB/buf): stage tile t+2 while computing t.
// 2 phases per K-tile, 16 MFMA each; counted vmcnt(4) once per tile.
// LDS chunk-XOR swizzle: phys chunk = logical ^ ((row>>1)&3) (0 conflicts,
// verified R3). Staged via linear gload_lds dest + pre-permuted global src.
// A [8192,K], B [N,K] row-major (K contiguous in both). C = A * B^T.
// EPI: 0 = store f16 to GH; 1 = GH[idx] = silu(GH[idx]) * acc (in-place);
//      2 = store f32 to OUT.
// =====================================================================
template <int K, int N, int EPI>
__global__ __launch_bounds__(512, 2) void gemm256(
    const _Float16* __restrict__ A,
    const _Float16* __restrict__ B,
    _Float16* __restrict__ GH,
    float* __restrict__ OUT) {
  constexpr int NT = K / 32;
  constexpr int NBC = N / 256;
  constexpr int NWG = (8192 / 256) * NBC;
  __shared__ __align__(16) _Float16 lds[3 * 16384];  // 96 KB

  const int t = threadIdx.x;       // 0..511
  const int lane = t & 63;
  const int wave = t >> 6;         // 0..7
  const int wm = wave >> 2;        // 0..1
  const int wn = wave & 3;         // 0..3

  // XCD-bijective swizzle (NWG % 8 == 0 for both instantiations)
  int bid = blockIdx.x;
  bid = (bid & 7) * (NWG >> 3) + (bid >> 3);
  const int bm = bid / NBC, bn = bid % NBC;

  // ---- staging addresses ----
  const int lc = (t & 3) ^ ((t >> 3) & 3);  // pre-permuted global chunk
  const _Float16* pA0 = A + ((long)bm * 256 + (t >> 2)) * K + lc * 8;
  const _Float16* pA1 = pA0 + (long)128 * K;
  const _Float16* pB0 = B + ((long)bn * 256 + (t >> 2)) * K + lc * 8;
  const _Float16* pB1 = pB0 + (long)128 * K;
  const int dA0 = t * 8, dA1 = 4096 + t * 8;          // f16 units, linear
  const int dB0 = 8192 + t * 8, dB1 = 12288 + t * 8;

  // ---- fragment read addresses (f16 units within buf) ----
  const int rA = wm * 128 + (lane & 15);
  const int rB = wn * 64 + (lane & 15);
  const int ckA = ((lane >> 4) ^ ((rA >> 1) & 3)) * 8;  // h(r+16i)==h(r)
  const int ckB = ((lane >> 4) ^ ((rB >> 1) & 3)) * 8;
  const int offA = rA * 32 + ckA;          // + i*512
  const int offB = 8192 + rB * 32 + ckB;   // + j*512

  // ---- prologue: stage tiles 0 (buf0) and 1 (buf1) ----
  gload16(pA0, lds + dA0);
  gload16(pA1, lds + dA1);
  gload16(pB0, lds + dB0);
  gload16(pB1, lds + dB1);
  gload16(pA0 + 32, lds + 16384 + dA0);
  gload16(pA1 + 32, lds + 16384 + dA1);
  gload16(pB0 + 32, lds + 16384 + dB0);
  gload16(pB1 + 32, lds + 16384 + dB1);
  pA0 += 64; pA1 += 64; pB0 += 64; pB1 += 64;  // -> tile 2
  asm volatile("s_waitcnt vmcnt(4)" ::: "memory");
  asm volatile("s_barrier" ::: "memory");
  __builtin_amdgcn_sched_barrier(0);

  floatx4 acc[8][4] = {};
  int buf = 0;

  for (int kt = 0; kt < NT; ++kt) {
    const _Float16* lb = lds + buf * 16384;
    const int sbuf = (buf == 0) ? 2 : buf - 1;  // (buf+2)%3
    _Float16* sb = lds + sbuf * 16384;
    const bool doStage = (kt + 2 < NT);

    // ---- phase A: issue all 12 ds_reads + 2 A-stage gloads ----
    half8 b[4], a[8];
#pragma unroll
    for (int j = 0; j < 4; ++j)
      b[j] = *reinterpret_cast<const half8*>(&lb[offB + j * 512]);
#pragma unroll
    for (int i = 0; i < 8; ++i)
      a[i] = *reinterpret_cast<const half8*>(&lb[offA + i * 512]);
    if (doStage) {
      gload16(pA0, sb + dA0);
      gload16(pA1, sb + dA1);
    }
    asm volatile("s_barrier" ::: "memory");
    __builtin_amdgcn_sched_barrier(0);
    __builtin_amdgcn_s_setprio(1);
#pragma unroll
    for (int i = 0; i < 4; ++i)
#pragma unroll
      for (int j = 0; j < 4; ++j)
        acc[i][j] = __builtin_amdgcn_mfma_f32_16x16x32_f16(a[i], b[j], acc[i][j], 0, 0, 0);
    __builtin_amdgcn_s_setprio(0);
    asm volatile("s_barrier" ::: "memory");
    __builtin_amdgcn_sched_barrier(0);

    // ---- phase B: 2 B-stage gloads + second MFMA quadrant ----
    if (doStage) {
      gload16(pB0, sb + dB0);
      gload16(pB1, sb + dB1);
      pA0 += 32; pA1 += 32; pB0 += 32; pB1 += 32;
    }
    __builtin_amdgcn_s_setprio(1);
#pragma unroll
    for (int i = 4; i < 8; ++i)
#pragma unroll
      for (int j = 0; j < 4; ++j)
        acc[i][j] = __builtin_amdgcn_mfma_f32_16x16x32_f16(a[i], b[j], acc[i][j], 0, 0, 0);
    __builtin_amdgcn_s_setprio(0);
    // counted vmcnt: tile t+1's 4 loads must be done; t+2's 4 may fly
    if (doStage) {
      asm volatile("s_waitcnt vmcnt(4)" ::: "memory");
    } else if (kt + 1 < NT) {
      asm volatile("s_waitcnt vmcnt(0)" ::: "memory");
    }
    asm volatile("s_barrier" ::: "memory");
    __builtin_amdgcn_sched_barrier(0);
    buf = (buf == 2) ? 0 : buf + 1;
  }

  // ---- epilogue ----
  const int r0 = bm * 256 + wm * 128 + (lane >> 4) * 4;
  const int c0 = bn * 256 + wn * 64 + (lane & 15);
#pragma unroll
  for (int i = 0; i < 8; ++i) {
#pragma unroll
    for (int j = 0; j < 4; ++j) {
#pragma unroll
      for (int ii = 0; ii < 4; ++ii) {
        const long idx = (long)(r0 + i * 16 + ii) * N + (c0 + j * 16);
        if (EPI == 0) {
          GH[idx] = (_Float16)acc[i][j][ii];
        } else if (EPI == 1) {
          float u = acc[i][j][ii];
          float g = (float)GH[idx];
          GH[idx] = (_Float16)(g / (1.0f + __expf(-g)) * u);
        } else {
          OUT[idx] = acc[i][j][ii];
        }
      }
    }
  }
}

extern "C" void kernel_launch(void* const* d_in, const int* in_sizes, int n_in,
                              void* d_out, int out_size, void* d_ws, size_t ws_size,
                              hipStream_t stream) {
  const float* x           = (const float*)d_in[0];
  const int*   gate_codes  = (const int*)d_in[1];
  const float* gate_scales = (const float*)d_in[2];
  const int*   up_codes    = (const int*)d_in[3];
  const float* up_scales   = (const float*)d_in[4];
  const int*   down_codes  = (const int*)d_in[5];
  const float* down_scales = (const float*)d_in[6];
  float* out = (float*)d_out;

  const long T = 8192, HD = 4096, M = 11008;

  // ws layout (fp16): x16 [T,HD] 67MB | W [M,HD] 90MB (reused 3x) | gh [T,M] 180MB
  char* ws = (char*)d_ws;
  _Float16* x16 = (_Float16*)ws;
  _Float16* W   = (_Float16*)(ws + T * HD * 2);
  _Float16* gh  = (_Float16*)(ws + T * HD * 2 + M * HD * 2);

  cvt_f32_to_f16<<<2048, 256, 0, stream>>>(x, x16, (int)(T * HD / 8));

  // gate: g = x @ Wg^T  -> gh (f16)
  dequant_nf4<<<2048, 256, 0, stream>>>(gate_codes, gate_scales, W,
                                        (int)(M * HD / 8), (int)HD, (int)(HD / 64));
  gemm256<4096, 11008, 0><<<(8192 / 256) * (11008 / 256), 512, 0, stream>>>(
      x16, W, gh, nullptr);

  // up + SwiGLU: gh = silu(gh) * (x @ Wu^T)   (in-place, element-exclusive)
  dequant_nf4<<<2048, 256, 0, stream>>>(up_codes, up_scales, W,
                                        (int)(M * HD / 8), (int)HD, (int)(HD / 64));
  gemm256<4096, 11008, 1><<<(8192 / 256) * (11008 / 256), 512, 0, stream>>>(
      x16, W, gh, nullptr);

  // down: out = gh @ Wd^T  (f32)
  dequant_nf4<<<2048, 256, 0, stream>>>(down_codes, down_scales, W,
                                        (int)(HD * M / 8), (int)M, (int)(M / 64));
  gemm256<11008, 4096, 2><<<(8192 / 256) * (4096 / 256), 512, 0, stream>>>(
      gh, W, nullptr, out);
}

// Round 5
// 2303.243 us; speedup vs baseline: 7.2560x; 1.0164x over previous
//
#include <hip/hip_runtime.h>
#include <hip/hip_bf16.h>

typedef _Float16 half8 __attribute__((ext_vector_type(8)));
typedef float floatx4 __attribute__((ext_vector_type(4)));

__device__ __constant__ float NF4_TAB[16] = {
    -1.0f, -0.6961928009986877f, -0.5250730514526367f, -0.39491748809814453f,
    -0.28444138169288635f, -0.18477343022823334f, -0.09105003625154495f, 0.0f,
    0.07958029955625534f, 0.16093020141124725f, 0.24611230194568634f,
    0.33791524171829224f, 0.44070982933044434f, 0.5626170039176941f,
    0.7229568362236023f, 1.0f};

typedef __attribute__((address_space(3))) void lds_t;
typedef __attribute__((address_space(1))) void gbl_t;

__device__ __forceinline__ void gload16(const void* g, void* l) {
  __builtin_amdgcn_global_load_lds((gbl_t*)g, (lds_t*)l, 16, 0, 0);
}

// ---------------- x f32 -> f16 ----------------
__global__ void cvt_f32_to_f16(const float* __restrict__ in,
                               _Float16* __restrict__ out, int total8) {
  int stride = gridDim.x * blockDim.x;
  for (int i = blockIdx.x * blockDim.x + threadIdx.x; i < total8; i += stride) {
    long e = (long)i * 8;
    const float4* ip = reinterpret_cast<const float4*>(in + e);
    float4 a = ip[0], b = ip[1];
    half8 o;
    o[0] = (_Float16)a.x; o[1] = (_Float16)a.y;
    o[2] = (_Float16)a.z; o[3] = (_Float16)a.w;
    o[4] = (_Float16)b.x; o[5] = (_Float16)b.y;
    o[6] = (_Float16)b.z; o[7] = (_Float16)b.w;
    *reinterpret_cast<half8*>(out + e) = o;
  }
}

// ---------------- NF4 dequant: codes[R,C] + scales[R,C/64] -> f16 [R,C] ----
__global__ void dequant_nf4(const int* __restrict__ codes,
                            const float* __restrict__ scales,
                            _Float16* __restrict__ out,
                            int total8, int C, int CB) {
  __shared__ float lut[16];
  if (threadIdx.x < 16) lut[threadIdx.x] = NF4_TAB[threadIdx.x];
  __syncthreads();
  int stride = gridDim.x * blockDim.x;
  for (int i = blockIdx.x * blockDim.x + threadIdx.x; i < total8; i += stride) {
    long e = (long)i * 8;
    int row = (int)(e / C);
    int col = (int)(e - (long)row * C);
    float sc = scales[row * CB + (col >> 6)];
    const int4* cp = reinterpret_cast<const int4*>(codes + e);
    int4 c0 = cp[0];
    int4 c1 = cp[1];
    half8 o;
    o[0] = (_Float16)(lut[c0.x & 15] * sc);
    o[1] = (_Float16)(lut[c0.y & 15] * sc);
    o[2] = (_Float16)(lut[c0.z & 15] * sc);
    o[3] = (_Float16)(lut[c0.w & 15] * sc);
    o[4] = (_Float16)(lut[c1.x & 15] * sc);
    o[5] = (_Float16)(lut[c1.y & 15] * sc);
    o[6] = (_Float16)(lut[c1.z & 15] * sc);
    o[7] = (_Float16)(lut[c1.w & 15] * sc);
    *reinterpret_cast<half8*>(out + e) = o;
  }
}

// =====================================================================
// 256x256 GEMM, BK=64, 8 waves (2Mx4N), per-wave 128x64 output.
// Double-buffered LDS (2 x 64 KB); each buffer = 4 slabs [256][32] f16:
//   A@kk0 (0), A@kk1 (8192), B@kk0 (16384), B@kk1 (24576).
// 4 phases/K-tile (kk-half x j-half), 16 MFMA each; one stage slot
// (2 gloads: rows 0-127, 128-255) per phase, targeting tile t+1:
//   P0->A0, P1->B0, P2->A1, P3->B1.
// Certification ledger (vmcnt counts 2 loads/slot, never 0 mid-loop):
//   P1: vmcnt(4) certifies A1,B1(t)   [staged P2,P3 of t-1; newer: P0,P1 of t]
//   P3: vmcnt(4) certifies A0,B0(t+1) [staged P0,P1 of t; newer: P2,P3 of t]
// Reads of a slab are always issued after a barrier that follows its
// certification. Chunk-XOR swizzle (phys = logical ^ ((row>>1)&3)): 0
// conflicts (verified R3/R4); linear gload_lds dest + permuted global src.
// EPI: 0 = f16 store; 1 = GH[idx]=silu(GH[idx])*acc (in-place); 2 = f32.
// =====================================================================
template <int K, int N, int EPI>
__global__ __launch_bounds__(512, 2) void gemm256(
    const _Float16* __restrict__ A,
    const _Float16* __restrict__ B,
    _Float16* __restrict__ GH,
    float* __restrict__ OUT) {
  constexpr int NT = K / 64;
  constexpr int NBC = N / 256;
  constexpr int NWG = (8192 / 256) * NBC;
  __shared__ __align__(16) _Float16 lds[2 * 32768];  // 128 KB

  const int t = threadIdx.x;       // 0..511
  const int lane = t & 63;
  const int wave = t >> 6;
  const int wm = wave >> 2;        // 0..1
  const int wn = wave & 3;         // 0..3

  // XCD-bijective swizzle (NWG % 8 == 0 for both instantiations)
  int bid = blockIdx.x;
  bid = (bid & 7) * (NWG >> 3) + (bid >> 3);
  const int bm = bid / NBC, bn = bid % NBC;

  // staging: round r in {0,1}: row=(t>>2)+128r, chunk lc=(t&3)^((t>>3)&3)
  // (h(row)=(row>>1)&3 == (t>>3)&3 for both rounds since 128r>>1 % 4 == 0)
  const int lc = (t & 3) ^ ((t >> 3) & 3);
  const _Float16* gA = A + ((long)bm * 256 + (t >> 2)) * K + lc * 8;
  const _Float16* gB = B + ((long)bn * 256 + (t >> 2)) * K + lc * 8;
  const long rstep = (long)128 * K;
  const int dst = t * 8;  // f16 units; +4096 for round 1 (wave-linear)

  // fragment read offsets (f16 units within buffer)
  const int rA = wm * 128 + (lane & 15);
  const int rB = wn * 64 + (lane & 15);
  const int ckA = ((lane >> 4) ^ ((rA >> 1) & 3)) * 8;  // h(r+16i)==h(r)
  const int ckB = ((lane >> 4) ^ ((rB >> 1) & 3)) * 8;
  const int offA = rA * 32 + ckA;           // + i*512 (+8192 for kk1)
  const int offB = 16384 + rB * 32 + ckB;   // + j*512 (+8192 for kk1)

#define STAGE_SLOT(gp, slab, koff, dbuf)                                   \
  gload16((gp) + (koff), lds + (dbuf) * 32768 + (slab) + dst);             \
  gload16((gp) + (koff) + rstep, lds + (dbuf) * 32768 + (slab) + dst + 4096);

  // ---- prologue: stage tile 0 -> buf0, order A0,B0,A1,B1 ----
  STAGE_SLOT(gA, 0, 0, 0);
  STAGE_SLOT(gB, 16384, 0, 0);
  STAGE_SLOT(gA, 8192, 32, 0);
  STAGE_SLOT(gB, 24576, 32, 0);
  gA += 64; gB += 64;
  asm volatile("s_waitcnt vmcnt(4)" ::: "memory");  // A0,B0(0) done
  __builtin_amdgcn_s_barrier();
  __builtin_amdgcn_sched_barrier(0);

  floatx4 acc[8][4] = {};

  for (int kt = 0; kt < NT; ++kt) {
    const int cb = kt & 1;
    const int sbuf = cb ^ 1;
    const _Float16* lb = lds + cb * 32768;
    const bool st = (kt + 1 < NT);
    const bool last = (kt == NT - 1);

    half8 a[8], b[2];

    // ---- P0: read a@kk0 x8 + b[0..1]@kk0; stage A0(t+1) ----
#pragma unroll
    for (int i = 0; i < 8; ++i)
      a[i] = *reinterpret_cast<const half8*>(&lb[offA + i * 512]);
    b[0] = *reinterpret_cast<const half8*>(&lb[offB]);
    b[1] = *reinterpret_cast<const half8*>(&lb[offB + 512]);
    if (st) { STAGE_SLOT(gA, 0, 0, sbuf); }
    __builtin_amdgcn_s_barrier();
    asm volatile("s_waitcnt lgkmcnt(0)" ::: "memory");
    __builtin_amdgcn_sched_barrier(0);
    __builtin_amdgcn_s_setprio(1);
#pragma unroll
    for (int i = 0; i < 8; ++i) {
      acc[i][0] = __builtin_amdgcn_mfma_f32_16x16x32_f16(a[i], b[0], acc[i][0], 0, 0, 0);
      acc[i][1] = __builtin_amdgcn_mfma_f32_16x16x32_f16(a[i], b[1], acc[i][1], 0, 0, 0);
    }
    __builtin_amdgcn_s_setprio(0);
    __builtin_amdgcn_s_barrier();
    __builtin_amdgcn_sched_barrier(0);

    // ---- P1: read b[2..3]@kk0; stage B0(t+1); certify A1,B1(t) ----
    b[0] = *reinterpret_cast<const half8*>(&lb[offB + 2 * 512]);
    b[1] = *reinterpret_cast<const half8*>(&lb[offB + 3 * 512]);
    if (st) { STAGE_SLOT(gB, 16384, 0, sbuf); }
    if (last) { asm volatile("s_waitcnt vmcnt(0)" ::: "memory"); }
    else      { asm volatile("s_waitcnt vmcnt(4)" ::: "memory"); }
    __builtin_amdgcn_s_barrier();
    asm volatile("s_waitcnt lgkmcnt(0)" ::: "memory");
    __builtin_amdgcn_sched_barrier(0);
    __builtin_amdgcn_s_setprio(1);
#pragma unroll
    for (int i = 0; i < 8; ++i) {
      acc[i][2] = __builtin_amdgcn_mfma_f32_16x16x32_f16(a[i], b[0], acc[i][2], 0, 0, 0);
      acc[i][3] = __builtin_amdgcn_mfma_f32_16x16x32_f16(a[i], b[1], acc[i][3], 0, 0, 0);
    }
    __builtin_amdgcn_s_setprio(0);
    __builtin_amdgcn_s_barrier();
    __builtin_amdgcn_sched_barrier(0);

    // ---- P2: read a@kk1 x8 + b[0..1]@kk1; stage A1(t+1) ----
#pragma unroll
    for (int i = 0; i < 8; ++i)
      a[i] = *reinterpret_cast<const half8*>(&lb[8192 + offA + i * 512]);
    b[0] = *reinterpret_cast<const half8*>(&lb[8192 + offB]);
    b[1] = *reinterpret_cast<const half8*>(&lb[8192 + offB + 512]);
    if (st) { STAGE_SLOT(gA, 8192, 32, sbuf); }
    __builtin_amdgcn_s_barrier();
    asm volatile("s_waitcnt lgkmcnt(0)" ::: "memory");
    __builtin_amdgcn_sched_barrier(0);
    __builtin_amdgcn_s_setprio(1);
#pragma unroll
    for (int i = 0; i < 8; ++i) {
      acc[i][0] = __builtin_amdgcn_mfma_f32_16x16x32_f16(a[i], b[0], acc[i][0], 0, 0, 0);
      acc[i][1] = __builtin_amdgcn_mfma_f32_16x16x32_f16(a[i], b[1], acc[i][1], 0, 0, 0);
    }
    __builtin_amdgcn_s_setprio(0);
    __builtin_amdgcn_s_barrier();
    __builtin_amdgcn_sched_barrier(0);

    // ---- P3: read b[2..3]@kk1; stage B1(t+1); certify A0,B0(t+1) ----
    b[0] = *reinterpret_cast<const half8*>(&lb[8192 + offB + 2 * 512]);
    b[1] = *reinterpret_cast<const half8*>(&lb[8192 + offB + 3 * 512]);
    if (st) { STAGE_SLOT(gB, 24576, 32, sbuf); gA += 64; gB += 64; }
    if (!last) { asm volatile("s_waitcnt vmcnt(4)" ::: "memory"); }
    __builtin_amdgcn_s_barrier();
    asm volatile("s_waitcnt lgkmcnt(0)" ::: "memory");
    __builtin_amdgcn_sched_barrier(0);
    __builtin_amdgcn_s_setprio(1);
#pragma unroll
    for (int i = 0; i < 8; ++i) {
      acc[i][2] = __builtin_amdgcn_mfma_f32_16x16x32_f16(a[i], b[0], acc[i][2], 0, 0, 0);
      acc[i][3] = __builtin_amdgcn_mfma_f32_16x16x32_f16(a[i], b[1], acc[i][3], 0, 0, 0);
    }
    __builtin_amdgcn_s_setprio(0);
    __builtin_amdgcn_s_barrier();
    __builtin_amdgcn_sched_barrier(0);
  }
#undef STAGE_SLOT

  // ---- epilogue ----
  const int r0 = bm * 256 + wm * 128 + (lane >> 4) * 4;
  const int c0 = bn * 256 + wn * 64 + (lane & 15);
#pragma unroll
  for (int i = 0; i < 8; ++i) {
#pragma unroll
    for (int j = 0; j < 4; ++j) {
#pragma unroll
      for (int ii = 0; ii < 4; ++ii) {
        const long idx = (long)(r0 + i * 16 + ii) * N + (c0 + j * 16);
        if (EPI == 0) {
          GH[idx] = (_Float16)acc[i][j][ii];
        } else if (EPI == 1) {
          float u = acc[i][j][ii];
          float g = (float)GH[idx];
          GH[idx] = (_Float16)(g / (1.0f + __expf(-g)) * u);
        } else {
          OUT[idx] = acc[i][j][ii];
        }
      }
    }
  }
}

extern "C" void kernel_launch(void* const* d_in, const int* in_sizes, int n_in,
                              void* d_out, int out_size, void* d_ws, size_t ws_size,
                              hipStream_t stream) {
  const float* x           = (const float*)d_in[0];
  const int*   gate_codes  = (const int*)d_in[1];
  const float* gate_scales = (const float*)d_in[2];
  const int*   up_codes    = (const int*)d_in[3];
  const float* up_scales   = (const float*)d_in[4];
  const int*   down_codes  = (const int*)d_in[5];
  const float* down_scales = (const float*)d_in[6];
  float* out = (float*)d_out;

  const long T = 8192, HD = 4096, M = 11008;

  // ws layout (fp16): x16 [T,HD] 67MB | W [M,HD] 90MB (reused 3x) | gh [T,M] 180MB
  char* ws = (char*)d_ws;
  _Float16* x16 = (_Float16*)ws;
  _Float16* W   = (_Float16*)(ws + T * HD * 2);
  _Float16* gh  = (_Float16*)(ws + T * HD * 2 + M * HD * 2);

  cvt_f32_to_f16<<<2048, 256, 0, stream>>>(x, x16, (int)(T * HD / 8));

  // gate: g = x @ Wg^T  -> gh (f16)
  dequant_nf4<<<2048, 256, 0, stream>>>(gate_codes, gate_scales, W,
                                        (int)(M * HD / 8), (int)HD, (int)(HD / 64));
  gemm256<4096, 11008, 0><<<(8192 / 256) * (11008 / 256), 512, 0, stream>>>(
      x16, W, gh, nullptr);

  // up + SwiGLU: gh = silu(gh) * (x @ Wu^T)   (in-place, element-exclusive)
  dequant_nf4<<<2048, 256, 0, stream>>>(up_codes, up_scales, W,
                                        (int)(M * HD / 8), (int)HD, (int)(HD / 64));
  gemm256<4096, 11008, 1><<<(8192 / 256) * (11008 / 256), 512, 0, stream>>>(
      x16, W, gh, nullptr);

  // down: out = gh @ Wd^T  (f32)
  dequant_nf4<<<2048, 256, 0, stream>>>(down_codes, down_scales, W,
                                        (int)(HD * M / 8), (int)M, (int)(M / 64));
  gemm256<11008, 4096, 2><<<(8192 / 256) * (4096 / 256), 512, 0, stream>>>(
      gh, W, nullptr, out);
}